// Round 12
// baseline (217.563 us; speedup 1.0000x reference)
//
#include <hip/hip_runtime.h>
#include <math.h>

constexpr int NB = 2;      // batch
constexpr int SL = 2048;   // sequence length
constexpr int NV = 1024;   // model dim
constexpr int NH = 16;     // heads
constexpr int DH = 64;     // head dim
constexpr float LN_EPS = 1e-3f;

typedef __bf16 bf16_t;
typedef __bf16 v8bf __attribute__((ext_vector_type(8)));
typedef float  v4f  __attribute__((ext_vector_type(4)));

__device__ __forceinline__ unsigned pack_bf16(float a, float b) {
  unsigned short ua = __builtin_bit_cast(unsigned short, (bf16_t)a);
  unsigned short ub = __builtin_bit_cast(unsigned short, (bf16_t)b);
  return (unsigned)ua | ((unsigned)ub << 16);
}
// async global->LDS, 16B/lane; LDS dest = wave-uniform base + lane*16.
__device__ __forceinline__ void async_cp16(const void* g, void* l) {
  __builtin_amdgcn_global_load_lds(
      (const __attribute__((address_space(1))) unsigned int*)g,
      (__attribute__((address_space(3))) unsigned int*)l, 16, 0, 0);
}
// Explicit drain of the global_load_lds DMA queue (vmcnt-tracked) before the
// barrier; verified R0->R2 as the fix for the warm-state buffer race.
__device__ __forceinline__ void drain_dma() {
  asm volatile("s_waitcnt vmcnt(0)" ::: "memory");
}

// ---------------------------------------------------------------------------
// W transpose+convert: W[h][v][d] fp32 -> Wt[z][n=h*64+d][v] bf16.
// Scale (1/8 * log2e) folded into Wq (softmax then uses exp2 directly).
__global__ __launch_bounds__(256)
void wcvt(const float* __restrict__ Wq, const float* __restrict__ Wk,
          const float* __restrict__ Wv, bf16_t* __restrict__ Wt) {
  __shared__ float ls[64][65];
  const int z = blockIdx.z;
  const float* W = z == 0 ? Wq : (z == 1 ? Wk : Wv);
  const float sc = z == 0 ? 0.125f * 1.44269504f : 1.0f;
  const int h = blockIdx.y, v0 = blockIdx.x * 64;
  const int t = threadIdx.x;
  const int rr = t >> 4, c4 = t & 15;
  const float* src = W + ((size_t)h * NV + v0) * DH;
#pragma unroll
  for (int it = 0; it < 4; ++it) {
    float4 f = *(const float4*)(src + (size_t)(rr + it * 16) * DH + c4 * 4);
    ls[rr + it * 16][c4 * 4 + 0] = f.x;
    ls[rr + it * 16][c4 * 4 + 1] = f.y;
    ls[rr + it * 16][c4 * 4 + 2] = f.z;
    ls[rr + it * 16][c4 * 4 + 3] = f.w;
  }
  __syncthreads();
  const int dd = t >> 2, vq = t & 3;
  bf16_t tmp[16];
#pragma unroll
  for (int i = 0; i < 16; ++i) tmp[i] = (bf16_t)(ls[vq * 16 + i][dd] * sc);
  bf16_t* dst = Wt + ((size_t)z * NV + h * 64 + dd) * NV + v0 + vq * 16;
  *(v8bf*)dst = *(v8bf*)&tmp[0];
  *(v8bf*)(dst + 8) = *(v8bf*)&tmp[8];
}

// ---------------------------------------------------------------------------
// Projection GEMM with FUSED fp32->bf16 A conversion (R11: acvt deleted).
// A staged as fp32 128B rows (8x16B chunks, XOR swz c=sc8^(r&7); read
// pattern enumerated: chunk=(2g)^(lx&7) covers all 32 banks uniformly =
// the wave64-b128 minimum). Fragment read: 2x b128 fp32 + cvt to bf16
// (~56 VALU/iter, co-scheduled with MFMA per m114). W path unchanged.
// LDS = 2x16KB A + 2x8KB W = 48KB -> 3 blocks/CU.
// Q/K outputs [bh][l][d]; V output TRANSPOSED [bh][d][m], vm folded in.
__global__ __launch_bounds__(256, 3)
void proj_mfma(const float* __restrict__ A0, const float* __restrict__ A1,
               const float* __restrict__ A2, const bf16_t* __restrict__ Wtb,
               const int* __restrict__ vmask,
               bf16_t* __restrict__ O0, bf16_t* __restrict__ O1,
               bf16_t* __restrict__ O2) {
  __shared__ __align__(16) float  Asb[2][128 * 32];  // fp32 [m][k], 128B rows
  __shared__ __align__(16) bf16_t Wsb[2][128 * 32];  // bf16 [n][k], 64B rows

  const int z = blockIdx.z;
  const float*  A   = z == 0 ? A0 : (z == 1 ? A1 : A2);
  bf16_t*       out = z == 0 ? O0 : (z == 1 ? O1 : O2);
  const bf16_t* W   = Wtb + (size_t)z * NV * NV;

  const int t = threadIdx.x, w = t >> 6, lane = t & 63;
  const int g = lane >> 4, lx = lane & 15;
  const int m0 = blockIdx.x * 128, n0 = blockIdx.y * 128;
  const int rbase = (w >> 1) * 64, cbase = (w & 1) * 64;

  // A: 8 rows/instr (8 lanes x 16B per row), 4 instrs per wave (32 rows).
  const int sr8 = lane >> 3, sc8 = lane & 7;
  auto stageA = [&](int k0, int buf) {
#pragma unroll
    for (int s = 0; s < 4; ++s) {
      const int r = w * 32 + s * 8 + sr8;
      const int c = sc8 ^ (r & 7);          // pre-swizzled source chunk
      async_cp16(A + (size_t)(m0 + r) * NV + k0 + c * 4,
                 (char*)Asb[buf] + (w * 32 + s * 8) * 128);
    }
  };
  // W: 16 rows/instr (4 lanes x 16B per row), 2 instrs per wave.
  const int sr = lane >> 2, sc = lane & 3;
  auto stageW = [&](int k0, int buf) {
#pragma unroll
    for (int s = 0; s < 2; ++s) {
      const int r = w * 32 + s * 16 + sr;
      const int c = sc ^ (r & 3);
      async_cp16(W + (size_t)(n0 + r) * NV + k0 + c * 8,
                 (char*)Wsb[buf] + (w * 32 + s * 16) * 64);
    }
  };

  v4f acc[4][4] = {};
  stageA(0, 0);
  stageW(0, 0);

  for (int it = 0; it < 32; ++it) {
    const int buf = it & 1;
    drain_dma();      // guarantee this iter's DMA landed
    __syncthreads();  // orders prev reads vs restage
    if (it < 31) {
      stageA((it + 1) * 32, buf ^ 1);
      stageW((it + 1) * 32, buf ^ 1);
    }
    v8bf af[4], wf[4];
#pragma unroll
    for (int rt = 0; rt < 4; ++rt) {
      const int row = rbase + rt * 16 + lx;
      const char* rb = (const char*)Asb[buf] + row * 128;
      const int p0 = (2 * g) ^ (row & 7);   // position of logical chunk 2g
      float4 fa = *(const float4*)(rb + p0 * 16);        // k = g*8 .. +3
      float4 fb = *(const float4*)(rb + (p0 ^ 1) * 16);  // k = g*8+4 .. +7
      uint4 u = {pack_bf16(fa.x, fa.y), pack_bf16(fa.z, fa.w),
                 pack_bf16(fb.x, fb.y), pack_bf16(fb.z, fb.w)};
      af[rt] = __builtin_bit_cast(v8bf, u);
    }
#pragma unroll
    for (int ct = 0; ct < 4; ++ct) {
      const int row = cbase + ct * 16 + lx;
      wf[ct] = *(const v8bf*)((const char*)Wsb[buf] + row * 64 +
                              ((g ^ (row & 3)) * 16));
    }
#pragma unroll
    for (int rt = 0; rt < 4; ++rt)
#pragma unroll
      for (int ct = 0; ct < 4; ++ct)
        acc[rt][ct] = __builtin_amdgcn_mfma_f32_16x16x32_bf16(
            af[rt], wf[ct], acc[rt][ct], 0, 0, 0);
  }

  // epilogue. C-layout: row=(lane>>4)*4+reg, col=lane&15.
  if (z < 2) {  // Q/K: [bh][l][d]
#pragma unroll
    for (int rt = 0; rt < 4; ++rt) {
#pragma unroll
      for (int reg = 0; reg < 4; ++reg) {
        const int row = m0 + rbase + rt * 16 + g * 4 + reg;
        const int b = row >> 11, l = row & (SL - 1);
#pragma unroll
        for (int ct = 0; ct < 4; ++ct) {
          const int n = n0 + cbase + ct * 16 + lx;
          const int h = n >> 6, d = n & 63;
          out[((size_t)(b * NH + h) * SL + l) * DH + d] = (bf16_t)acc[rt][ct][reg];
        }
      }
    }
  } else {  // V: transposed [bh][d][m], vm folded in; b64 stores along m
#pragma unroll
    for (int rt = 0; rt < 4; ++rt) {
      const int row = m0 + rbase + rt * 16 + g * 4;  // regs = 4 consecutive m
      const int b = row >> 11, l = row & (SL - 1);
      float vm0 = (float)vmask[b * SL + l + 0];
      float vm1 = (float)vmask[b * SL + l + 1];
      float vm2 = (float)vmask[b * SL + l + 2];
      float vm3 = (float)vmask[b * SL + l + 3];
#pragma unroll
      for (int ct = 0; ct < 4; ++ct) {
        const int n = n0 + cbase + ct * 16 + lx;
        const int h = n >> 6, d = n & 63;
        uint2 u = {pack_bf16(acc[rt][ct][0] * vm0, acc[rt][ct][1] * vm1),
                   pack_bf16(acc[rt][ct][2] * vm2, acc[rt][ct][3] * vm3)};
        *(uint2*)&out[((size_t)(b * NH + h) * DH + d) * SL + l] = u;
      }
    }
  }
}

// ---------------------------------------------------------------------------
// Fused attention — exact R3 structure (best measured: 51.5us), plus the
// residual fold: epilogue writes O*inv + query (ln then reads one stream).
// q-tile 64, grid 1024 -> 4 blocks/CU (LDS 40KB). Per wave: 16 q x all m.
// Softmax denominator over ALL m (unmasked, keras semantics); PV masked by
// tril (vm folded into V^T); qm at epilogue. exp2, no max-tracking.
// K/V^T double-buffered via global_load_lds, one barrier per 64-m tile;
// P round-trip via wave-private XOR-swizzled LDS (128B rows).
__global__ __launch_bounds__(256, 4)
void attn_mfma(const bf16_t* __restrict__ Qg, const bf16_t* __restrict__ Kg,
               const bf16_t* __restrict__ Vtg_all, const int* __restrict__ qmask,
               const float* __restrict__ queryg, float* __restrict__ Xout) {
  __shared__ __align__(16) bf16_t kbuf[2][64 * 64];  // K[m][d], XOR swz  16KB
  __shared__ __align__(16) bf16_t vbuf[2][64 * 64];  // V^T[d][m], XOR swz 16KB
  __shared__ __align__(16) bf16_t Ps[4][16 * 64];    // per-wave P^T, swz   8KB

  const int id = blockIdx.x;
  const int bh = (id & 7) | ((id >> 8) << 3);
  const int qraw = (id >> 3) & 31;
  const int qb = ((id >> 8) & 1) ? qraw : 31 - qraw;  // complement pairing
  const int t = threadIdx.x, w = t >> 6, lane = t & 63;
  const int g = lane >> 4, lx = lane & 15;
  const int b = bh >> 4, h = bh & 15;
  const int l0 = qb * 64;
  const int lastAct = qb;                     // diagonal tile index

  const bf16_t* Kb  = Kg + (size_t)bh * SL * DH;
  const bf16_t* Vtg = Vtg_all + (size_t)bh * DH * SL;  // [d][m]

  // persistent Q B-frags: wave covers q in [l0 + w*16, +16)
  v8bf qf[2];
#pragma unroll
  for (int ks = 0; ks < 2; ++ks)
    qf[ks] = *(const v8bf*)&Qg[((size_t)bh * SL + l0 + w * 16 + lx) * DH +
                               ks * 32 + g * 8];

  v4f O[4] = {};          // [dt]
  float suml = 0.f;

  const int sr_off = lane >> 3, sc_l = lane & 7;
  auto stageK = [&](int mb, int buf) {
#pragma unroll
    for (int s = 0; s < 2; ++s) {
      const int r = w * 16 + s * 8 + sr_off;
      const int c = sc_l ^ (r & 7);
      async_cp16(Kb + (size_t)(mb + r) * DH + c * 8,
                 (char*)kbuf[buf] + (w * 16 + s * 8) * 128);
    }
  };
  auto stageV = [&](int mb, int buf) {
#pragma unroll
    for (int s = 0; s < 2; ++s) {
      const int r = w * 16 + s * 8 + sr_off;  // r = d row
      const int c = sc_l ^ (r & 7);
      async_cp16(Vtg + (size_t)r * SL + mb + c * 8,
                 (char*)vbuf[buf] + (w * 16 + s * 8) * 128);
    }
  };

  stageK(0, 0);
  stageV(0, 0);

  // ---- active tiles (causal overlap with [l0, l0+64)): S, P, PV ----
  for (int mt = 0; mt <= lastAct; ++mt) {
    const int pb = mt & 1;
    drain_dma();      // guarantee tile mt's DMA landed
    __syncthreads();  // orders prev reads vs restage
    if (mt < SL / 64 - 1)  stageK((mt + 1) * 64, pb ^ 1);
    if (mt + 1 <= lastAct) stageV((mt + 1) * 64, pb ^ 1);

    // S^T: rows = m (mt2*16 + g*4 + reg), cols = q (lx)
    v4f S[4];
#pragma unroll
    for (int mt2 = 0; mt2 < 4; ++mt2) S[mt2] = (v4f){0.f, 0.f, 0.f, 0.f};
#pragma unroll
    for (int ks = 0; ks < 2; ++ks)
#pragma unroll
      for (int mt2 = 0; mt2 < 4; ++mt2) {
        const int row = mt2 * 16 + lx;
        v8bf kf = *(const v8bf*)((const char*)kbuf[pb] + row * 128 +
                                 (((ks * 4 + g) ^ (lx & 7)) * 16));
        S[mt2] = __builtin_amdgcn_mfma_f32_16x16x32_bf16(kf, qf[ks], S[mt2],
                                                         0, 0, 0);
      }

    const bool diagzone = (mt == qb);  // only the diagonal tile straddles
#pragma unroll
    for (int mt2 = 0; mt2 < 4; ++mt2) {
      float e0 = __builtin_amdgcn_exp2f(S[mt2][0]);
      float e1 = __builtin_amdgcn_exp2f(S[mt2][1]);
      float e2 = __builtin_amdgcn_exp2f(S[mt2][2]);
      float e3 = __builtin_amdgcn_exp2f(S[mt2][3]);
      suml += (e0 + e1) + (e2 + e3);  // denominator: unmasked
      if (diagzone) {
        const int ml = mt * 64 + mt2 * 16 + g * 4;
        const int ql = l0 + w * 16 + lx;
        e0 = (ml + 0 <= ql) ? e0 : 0.f;
        e1 = (ml + 1 <= ql) ? e1 : 0.f;
        e2 = (ml + 2 <= ql) ? e2 : 0.f;
        e3 = (ml + 3 <= ql) ? e3 : 0.f;
      }
      uint2 u = {pack_bf16(e0, e1), pack_bf16(e2, e3)};
      // swizzled store: row q=lx (128B), 8B chunk at (mt2*32+g*8)^((lx&7)<<4)
      *(uint2*)((char*)Ps[w] + lx * 128 +
                ((mt2 * 32 + g * 8) ^ ((lx & 7) << 4))) = u;
    }

    // compiler fence for the same-wave LDS round-trip (HW same-wave DS
    // ordering makes it correct; this only forbids C-level reordering).
    __builtin_amdgcn_wave_barrier();

    // O += P . V   (Ps wave-private)
#pragma unroll
    for (int ks = 0; ks < 2; ++ks) {
      v8bf pf = *(const v8bf*)((const char*)Ps[w] + lx * 128 +
                               ((ks * 64 + g * 16) ^ ((lx & 7) << 4)));
#pragma unroll
      for (int dt = 0; dt < 4; ++dt) {
        const int row = dt * 16 + lx;
        v8bf vf = *(const v8bf*)((const char*)vbuf[pb] + row * 128 +
                                 (((ks * 4 + g) ^ (lx & 7)) * 16));
        O[dt] = __builtin_amdgcn_mfma_f32_16x16x32_bf16(pf, vf, O[dt],
                                                        0, 0, 0);
      }
    }
  }

  // ---- future tiles: denominator only ----
  for (int mt = lastAct + 1; mt < SL / 64; ++mt) {
    const int pb = mt & 1;
    drain_dma();
    __syncthreads();
    if (mt < SL / 64 - 1) stageK((mt + 1) * 64, pb ^ 1);
    v4f S[4];
#pragma unroll
    for (int mt2 = 0; mt2 < 4; ++mt2) S[mt2] = (v4f){0.f, 0.f, 0.f, 0.f};
#pragma unroll
    for (int ks = 0; ks < 2; ++ks)
#pragma unroll
      for (int mt2 = 0; mt2 < 4; ++mt2) {
        const int row = mt2 * 16 + lx;
        v8bf kf = *(const v8bf*)((const char*)kbuf[pb] + row * 128 +
                                 (((ks * 4 + g) ^ (lx & 7)) * 16));
        S[mt2] = __builtin_amdgcn_mfma_f32_16x16x32_bf16(kf, qf[ks], S[mt2],
                                                         0, 0, 0);
      }
#pragma unroll
    for (int mt2 = 0; mt2 < 4; ++mt2)
      suml += (__builtin_amdgcn_exp2f(S[mt2][0]) +
               __builtin_amdgcn_exp2f(S[mt2][1])) +
              (__builtin_amdgcn_exp2f(S[mt2][2]) +
               __builtin_amdgcn_exp2f(S[mt2][3]));
  }

  // ---- wave-private epilogue (no barrier); residual fold: + query ----
  suml += __shfl_xor(suml, 16);
  suml += __shfl_xor(suml, 32);
#pragma unroll
  for (int reg = 0; reg < 4; ++reg) {
    const int q = l0 + w * 16 + g * 4 + reg;
    const float den = __shfl(suml, g * 4 + reg);
    const float inv = (float)qmask[b * SL + q] / den;
    const size_t rowoff = ((size_t)(b * SL + q)) * NV + h * DH;
#pragma unroll
    for (int dt = 0; dt < 4; ++dt)
      Xout[rowoff + dt * 16 + lx] =
          O[dt][reg] * inv + queryg[rowoff + dt * 16 + lx];
  }
}

// ---------------------------------------------------------------------------
// LayerNorm over last dim (V=1024); input X already contains the residual
// (folded into attn epilogue). Wave-per-row, zero barriers: 4 rows/block,
// lane owns columns lane*4 + i*256, full reduction via shfl_xor butterfly.
__global__ __launch_bounds__(256)
void ln_kernel(const float* __restrict__ X,
               const float* __restrict__ gamma, const float* __restrict__ beta,
               float* __restrict__ out) {
  const int row = blockIdx.x * 4 + (threadIdx.x >> 6);
  const int lane = threadIdx.x & 63;
  const float* xr = X + (size_t)row * NV;
  float4 y[4];
  float s = 0.f, ss = 0.f;
#pragma unroll
  for (int i = 0; i < 4; ++i) {
    const int col = lane * 4 + i * 256;
    y[i] = *(const float4*)(xr + col);
    s  += (y[i].x + y[i].y) + (y[i].z + y[i].w);
    ss += (y[i].x * y[i].x + y[i].y * y[i].y) +
          (y[i].z * y[i].z + y[i].w * y[i].w);
  }
#pragma unroll
  for (int off = 1; off < 64; off <<= 1) {
    s  += __shfl_xor(s, off);
    ss += __shfl_xor(ss, off);
  }
  const float mu   = s * (1.f / NV);
  const float var  = ss * (1.f / NV) - mu * mu;
  const float rstd = rsqrtf(var + LN_EPS);
#pragma unroll
  for (int i = 0; i < 4; ++i) {
    const int col = lane * 4 + i * 256;
    float4 gv = *(const float4*)(gamma + col);
    float4 bv = *(const float4*)(beta + col);
    float4 o;
    o.x = gv.x * (y[i].x - mu) * rstd + bv.x;
    o.y = gv.y * (y[i].y - mu) * rstd + bv.y;
    o.z = gv.z * (y[i].z - mu) * rstd + bv.z;
    o.w = gv.w * (y[i].w - mu) * rstd + bv.w;
    *(float4*)(out + (size_t)row * NV + col) = o;
  }
}

// ---------------------------------------------------------------------------
extern "C" void kernel_launch(void* const* d_in, const int* in_sizes, int n_in,
                              void* d_out, int out_size, void* d_ws, size_t ws_size,
                              hipStream_t stream) {
  const float* query = (const float*)d_in[0];
  const float* key_t = (const float*)d_in[1];
  const float* value = (const float*)d_in[2];
  const float* Wq    = (const float*)d_in[3];
  const float* Wk    = (const float*)d_in[4];
  const float* Wv    = (const float*)d_in[5];
  const float* gamma = (const float*)d_in[6];
  const float* beta  = (const float*)d_in[7];
  const int*   qmask = (const int*)d_in[8];
  const int*   vmask = (const int*)d_in[9];
  float* out = (float*)d_out;

  const size_t per = (size_t)NB * NH * SL * DH;  // 4,194,304 elements
  bf16_t* Qws = (bf16_t*)d_ws;
  bf16_t* Kws = Qws + per;
  bf16_t* Vws = Kws + per;   // transposed [bh][d][m], vm-masked
  bf16_t* Wtb = Vws + per;   // 3 * 1024*1024 bf16 = 6 MB

  wcvt<<<dim3(16, 16, 3), 256, 0, stream>>>(Wq, Wk, Wv, Wtb);
  proj_mfma<<<dim3(32, 8, 3), 256, 0, stream>>>(query, key_t, value, Wtb,
                                                vmask, Qws, Kws, Vws);
  attn_mfma<<<1024, 256, 0, stream>>>(Qws, Kws, Vws, qmask, query, out);
  ln_kernel<<<NB * SL / 4, 256, 0, stream>>>(out, gamma, beta, out);
}

// Round 13
// 201.325 us; speedup vs baseline: 1.0807x; 1.0807x over previous
//
#include <hip/hip_runtime.h>
#include <math.h>

constexpr int NB = 2;      // batch
constexpr int SL = 2048;   // sequence length
constexpr int NV = 1024;   // model dim
constexpr int NH = 16;     // heads
constexpr int DH = 64;     // head dim
constexpr float LN_EPS = 1e-3f;

typedef __bf16 bf16_t;
typedef __bf16 v8bf __attribute__((ext_vector_type(8)));
typedef float  v4f  __attribute__((ext_vector_type(4)));

__device__ __forceinline__ unsigned pack_bf16(float a, float b) {
  unsigned short ua = __builtin_bit_cast(unsigned short, (bf16_t)a);
  unsigned short ub = __builtin_bit_cast(unsigned short, (bf16_t)b);
  return (unsigned)ua | ((unsigned)ub << 16);
}
// async global->LDS, 16B/lane; LDS dest = wave-uniform base + lane*16.
__device__ __forceinline__ void async_cp16(const void* g, void* l) {
  __builtin_amdgcn_global_load_lds(
      (const __attribute__((address_space(1))) unsigned int*)g,
      (__attribute__((address_space(3))) unsigned int*)l, 16, 0, 0);
}
// Explicit drain of the global_load_lds DMA queue (vmcnt-tracked) before the
// barrier; verified R0->R2 as the fix for the warm-state buffer race.
__device__ __forceinline__ void drain_dma() {
  asm volatile("s_waitcnt vmcnt(0)" ::: "memory");
}

// ---------------------------------------------------------------------------
// prep = acvt + wcvt merged (R13: one launch fewer; both are independent
// preprocessing). Blocks [0,12288): fp32->bf16 cast of q/k/v (4096 each,
// fully coalesced float4->uint2). Blocks [12288,13056): W transpose+convert
// W[h][v][d] -> Wt[z][n=h*64+d][v] bf16, scale (1/8*log2e) folded into Wq.
__global__ __launch_bounds__(256)
void prep(const float* __restrict__ q, const float* __restrict__ k,
          const float* __restrict__ v, const float* __restrict__ Wq,
          const float* __restrict__ Wk, const float* __restrict__ Wv,
          bf16_t* __restrict__ oq, bf16_t* __restrict__ ok,
          bf16_t* __restrict__ ov, bf16_t* __restrict__ Wt) {
  __shared__ float ls[64][65];
  const int bid = blockIdx.x;
  const int t = threadIdx.x;
  if (bid < 12288) {  // ---- acvt part ----
    const int z = bid >> 12;
    const int bx = bid & 4095;
    const float* src = z == 0 ? q : (z == 1 ? k : v);
    bf16_t*      dst = z == 0 ? oq : (z == 1 ? ok : ov);
    const size_t i = ((size_t)bx * 256 + t) * 4;
    float4 f = *(const float4*)(src + i);
    uint2 u = {pack_bf16(f.x, f.y), pack_bf16(f.z, f.w)};
    *(uint2*)(dst + i) = u;
    return;
  }
  // ---- wcvt part ----
  const int idx = bid - 12288;
  const int z = idx >> 8, h = (idx >> 4) & 15, v0 = (idx & 15) * 64;
  const float* W = z == 0 ? Wq : (z == 1 ? Wk : Wv);
  const float sc = z == 0 ? 0.125f * 1.44269504f : 1.0f;
  const int rr = t >> 4, c4 = t & 15;
  const float* src = W + ((size_t)h * NV + v0) * DH;
#pragma unroll
  for (int it = 0; it < 4; ++it) {
    float4 f = *(const float4*)(src + (size_t)(rr + it * 16) * DH + c4 * 4);
    ls[rr + it * 16][c4 * 4 + 0] = f.x;
    ls[rr + it * 16][c4 * 4 + 1] = f.y;
    ls[rr + it * 16][c4 * 4 + 2] = f.z;
    ls[rr + it * 16][c4 * 4 + 3] = f.w;
  }
  __syncthreads();
  const int dd = t >> 2, vq = t & 3;
  bf16_t tmp[16];
#pragma unroll
  for (int i = 0; i < 16; ++i) tmp[i] = (bf16_t)(ls[vq * 16 + i][dd] * sc);
  bf16_t* dst = Wt + ((size_t)z * NV + h * 64 + dd) * NV + v0 + vq * 16;
  *(v8bf*)dst = *(v8bf*)&tmp[0];
  *(v8bf*)(dst + 8) = *(v8bf*)&tmp[8];
}

// ---------------------------------------------------------------------------
// Projection GEMM, ALL-bf16 (A pre-cast by prep) — exact R2 structure
// (proven: never in top-5, <=53us). BK=32, double-buffered, ONE barrier/iter,
// 32KB LDS -> 4 blocks/CU. Both operands DMA-staged as 64B rows, XOR swz.
// Q/K outputs [bh][l][d]; V output TRANSPOSED [bh][d][m], vm folded in.
// (R12's fused fp32-A variant REVERTED: cast-once amortization matters —
// fp32 re-fetch x8 n-blocks doubled FETCH, + 4.7M bank conflicts.)
__global__ __launch_bounds__(256, 4)
void proj_mfma(const bf16_t* __restrict__ A0, const bf16_t* __restrict__ A1,
               const bf16_t* __restrict__ A2, const bf16_t* __restrict__ Wtb,
               const int* __restrict__ vmask,
               bf16_t* __restrict__ O0, bf16_t* __restrict__ O1,
               bf16_t* __restrict__ O2) {
  __shared__ __align__(16) bf16_t Asb[2][128 * 32];  // [m][k] 64B rows, XOR swz
  __shared__ __align__(16) bf16_t Wsb[2][128 * 32];  // [n][k] 64B rows, XOR swz

  const int z = blockIdx.z;
  const bf16_t* A   = z == 0 ? A0 : (z == 1 ? A1 : A2);
  bf16_t*       out = z == 0 ? O0 : (z == 1 ? O1 : O2);
  const bf16_t* W   = Wtb + (size_t)z * NV * NV;

  const int t = threadIdx.x, w = t >> 6, lane = t & 63;
  const int g = lane >> 4, lx = lane & 15;
  const int m0 = blockIdx.x * 128, n0 = blockIdx.y * 128;
  const int rbase = (w >> 1) * 64, cbase = (w & 1) * 64;

  const int sr = lane >> 2;           // 16 rows per instr, 4 lanes/row
  const int sc = (lane & 3);
  auto stageA = [&](int k0, int buf) {
#pragma unroll
    for (int s = 0; s < 2; ++s) {
      const int r = w * 32 + s * 16 + sr;
      const int c = sc ^ (r & 3);
      async_cp16(A + (size_t)(m0 + r) * NV + k0 + c * 8,
                 (char*)Asb[buf] + (w * 32 + s * 16) * 64);
    }
  };
  auto stageW = [&](int k0, int buf) {
#pragma unroll
    for (int s = 0; s < 2; ++s) {
      const int r = w * 32 + s * 16 + sr;
      const int c = sc ^ (r & 3);
      async_cp16(W + (size_t)(n0 + r) * NV + k0 + c * 8,
                 (char*)Wsb[buf] + (w * 32 + s * 16) * 64);
    }
  };

  v4f acc[4][4] = {};
  stageA(0, 0);
  stageW(0, 0);

  for (int it = 0; it < 32; ++it) {
    const int buf = it & 1;
    drain_dma();      // guarantee this iter's DMA landed
    __syncthreads();  // orders prev reads vs restage
    if (it < 31) {
      stageA((it + 1) * 32, buf ^ 1);
      stageW((it + 1) * 32, buf ^ 1);
    }
    v8bf af[4], wf[4];
#pragma unroll
    for (int rt = 0; rt < 4; ++rt) {
      const int row = rbase + rt * 16 + lx;
      af[rt] = *(const v8bf*)((const char*)Asb[buf] + row * 64 +
                              ((g ^ (row & 3)) * 16));
    }
#pragma unroll
    for (int ct = 0; ct < 4; ++ct) {
      const int row = cbase + ct * 16 + lx;
      wf[ct] = *(const v8bf*)((const char*)Wsb[buf] + row * 64 +
                              ((g ^ (row & 3)) * 16));
    }
#pragma unroll
    for (int rt = 0; rt < 4; ++rt)
#pragma unroll
      for (int ct = 0; ct < 4; ++ct)
        acc[rt][ct] = __builtin_amdgcn_mfma_f32_16x16x32_bf16(
            af[rt], wf[ct], acc[rt][ct], 0, 0, 0);
  }

  // epilogue. C-layout: row=(lane>>4)*4+reg, col=lane&15.
  if (z < 2) {  // Q/K: [bh][l][d]
#pragma unroll
    for (int rt = 0; rt < 4; ++rt) {
#pragma unroll
      for (int reg = 0; reg < 4; ++reg) {
        const int row = m0 + rbase + rt * 16 + g * 4 + reg;
        const int b = row >> 11, l = row & (SL - 1);
#pragma unroll
        for (int ct = 0; ct < 4; ++ct) {
          const int n = n0 + cbase + ct * 16 + lx;
          const int h = n >> 6, d = n & 63;
          out[((size_t)(b * NH + h) * SL + l) * DH + d] = (bf16_t)acc[rt][ct][reg];
        }
      }
    }
  } else {  // V: transposed [bh][d][m], vm folded in; b64 stores along m
#pragma unroll
    for (int rt = 0; rt < 4; ++rt) {
      const int row = m0 + rbase + rt * 16 + g * 4;  // regs = 4 consecutive m
      const int b = row >> 11, l = row & (SL - 1);
      float vm0 = (float)vmask[b * SL + l + 0];
      float vm1 = (float)vmask[b * SL + l + 1];
      float vm2 = (float)vmask[b * SL + l + 2];
      float vm3 = (float)vmask[b * SL + l + 3];
#pragma unroll
      for (int ct = 0; ct < 4; ++ct) {
        const int n = n0 + cbase + ct * 16 + lx;
        const int h = n >> 6, d = n & 63;
        uint2 u = {pack_bf16(acc[rt][ct][0] * vm0, acc[rt][ct][1] * vm1),
                   pack_bf16(acc[rt][ct][2] * vm2, acc[rt][ct][3] * vm3)};
        *(uint2*)&out[((size_t)(b * NH + h) * DH + d) * SL + l] = u;
      }
    }
  }
}

// ---------------------------------------------------------------------------
// Fused attention — exact R3 structure (best measured: 51.5us), plus the
// residual fold: epilogue writes O*inv + query (ln then reads one stream).
// q-tile 64, grid 1024 -> 4 blocks/CU (LDS 40KB). Per wave: 16 q x all m.
// Softmax denominator over ALL m (unmasked, keras semantics); PV masked by
// tril (vm folded into V^T); qm at epilogue. exp2, no max-tracking.
// K/V^T double-buffered via global_load_lds, one barrier per 64-m tile;
// P round-trip via wave-private XOR-swizzled LDS (128B rows).
__global__ __launch_bounds__(256, 4)
void attn_mfma(const bf16_t* __restrict__ Qg, const bf16_t* __restrict__ Kg,
               const bf16_t* __restrict__ Vtg_all, const int* __restrict__ qmask,
               const float* __restrict__ queryg, float* __restrict__ Xout) {
  __shared__ __align__(16) bf16_t kbuf[2][64 * 64];  // K[m][d], XOR swz  16KB
  __shared__ __align__(16) bf16_t vbuf[2][64 * 64];  // V^T[d][m], XOR swz 16KB
  __shared__ __align__(16) bf16_t Ps[4][16 * 64];    // per-wave P^T, swz   8KB

  const int id = blockIdx.x;
  const int bh = (id & 7) | ((id >> 8) << 3);
  const int qraw = (id >> 3) & 31;
  const int qb = ((id >> 8) & 1) ? qraw : 31 - qraw;  // complement pairing
  const int t = threadIdx.x, w = t >> 6, lane = t & 63;
  const int g = lane >> 4, lx = lane & 15;
  const int b = bh >> 4, h = bh & 15;
  const int l0 = qb * 64;
  const int lastAct = qb;                     // diagonal tile index

  const bf16_t* Kb  = Kg + (size_t)bh * SL * DH;
  const bf16_t* Vtg = Vtg_all + (size_t)bh * DH * SL;  // [d][m]

  // persistent Q B-frags: wave covers q in [l0 + w*16, +16)
  v8bf qf[2];
#pragma unroll
  for (int ks = 0; ks < 2; ++ks)
    qf[ks] = *(const v8bf*)&Qg[((size_t)bh * SL + l0 + w * 16 + lx) * DH +
                               ks * 32 + g * 8];

  v4f O[4] = {};          // [dt]
  float suml = 0.f;

  const int sr_off = lane >> 3, sc_l = lane & 7;
  auto stageK = [&](int mb, int buf) {
#pragma unroll
    for (int s = 0; s < 2; ++s) {
      const int r = w * 16 + s * 8 + sr_off;
      const int c = sc_l ^ (r & 7);
      async_cp16(Kb + (size_t)(mb + r) * DH + c * 8,
                 (char*)kbuf[buf] + (w * 16 + s * 8) * 128);
    }
  };
  auto stageV = [&](int mb, int buf) {
#pragma unroll
    for (int s = 0; s < 2; ++s) {
      const int r = w * 16 + s * 8 + sr_off;  // r = d row
      const int c = sc_l ^ (r & 7);
      async_cp16(Vtg + (size_t)r * SL + mb + c * 8,
                 (char*)vbuf[buf] + (w * 16 + s * 8) * 128);
    }
  };

  stageK(0, 0);
  stageV(0, 0);

  // ---- active tiles (causal overlap with [l0, l0+64)): S, P, PV ----
  for (int mt = 0; mt <= lastAct; ++mt) {
    const int pb = mt & 1;
    drain_dma();      // guarantee tile mt's DMA landed
    __syncthreads();  // orders prev reads vs restage
    if (mt < SL / 64 - 1)  stageK((mt + 1) * 64, pb ^ 1);
    if (mt + 1 <= lastAct) stageV((mt + 1) * 64, pb ^ 1);

    // S^T: rows = m (mt2*16 + g*4 + reg), cols = q (lx)
    v4f S[4];
#pragma unroll
    for (int mt2 = 0; mt2 < 4; ++mt2) S[mt2] = (v4f){0.f, 0.f, 0.f, 0.f};
#pragma unroll
    for (int ks = 0; ks < 2; ++ks)
#pragma unroll
      for (int mt2 = 0; mt2 < 4; ++mt2) {
        const int row = mt2 * 16 + lx;
        v8bf kf = *(const v8bf*)((const char*)kbuf[pb] + row * 128 +
                                 (((ks * 4 + g) ^ (lx & 7)) * 16));
        S[mt2] = __builtin_amdgcn_mfma_f32_16x16x32_bf16(kf, qf[ks], S[mt2],
                                                         0, 0, 0);
      }

    const bool diagzone = (mt == qb);  // only the diagonal tile straddles
#pragma unroll
    for (int mt2 = 0; mt2 < 4; ++mt2) {
      float e0 = __builtin_amdgcn_exp2f(S[mt2][0]);
      float e1 = __builtin_amdgcn_exp2f(S[mt2][1]);
      float e2 = __builtin_amdgcn_exp2f(S[mt2][2]);
      float e3 = __builtin_amdgcn_exp2f(S[mt2][3]);
      suml += (e0 + e1) + (e2 + e3);  // denominator: unmasked
      if (diagzone) {
        const int ml = mt * 64 + mt2 * 16 + g * 4;
        const int ql = l0 + w * 16 + lx;
        e0 = (ml + 0 <= ql) ? e0 : 0.f;
        e1 = (ml + 1 <= ql) ? e1 : 0.f;
        e2 = (ml + 2 <= ql) ? e2 : 0.f;
        e3 = (ml + 3 <= ql) ? e3 : 0.f;
      }
      uint2 u = {pack_bf16(e0, e1), pack_bf16(e2, e3)};
      // swizzled store: row q=lx (128B), 8B chunk at (mt2*32+g*8)^((lx&7)<<4)
      *(uint2*)((char*)Ps[w] + lx * 128 +
                ((mt2 * 32 + g * 8) ^ ((lx & 7) << 4))) = u;
    }

    // compiler fence for the same-wave LDS round-trip (HW same-wave DS
    // ordering makes it correct; this only forbids C-level reordering).
    __builtin_amdgcn_wave_barrier();

    // O += P . V   (Ps wave-private)
#pragma unroll
    for (int ks = 0; ks < 2; ++ks) {
      v8bf pf = *(const v8bf*)((const char*)Ps[w] + lx * 128 +
                               ((ks * 64 + g * 16) ^ ((lx & 7) << 4)));
#pragma unroll
      for (int dt = 0; dt < 4; ++dt) {
        const int row = dt * 16 + lx;
        v8bf vf = *(const v8bf*)((const char*)vbuf[pb] + row * 128 +
                                 (((ks * 4 + g) ^ (lx & 7)) * 16));
        O[dt] = __builtin_amdgcn_mfma_f32_16x16x32_bf16(pf, vf, O[dt],
                                                        0, 0, 0);
      }
    }
  }

  // ---- future tiles: denominator only ----
  for (int mt = lastAct + 1; mt < SL / 64; ++mt) {
    const int pb = mt & 1;
    drain_dma();
    __syncthreads();
    if (mt < SL / 64 - 1) stageK((mt + 1) * 64, pb ^ 1);
    v4f S[4];
#pragma unroll
    for (int mt2 = 0; mt2 < 4; ++mt2) S[mt2] = (v4f){0.f, 0.f, 0.f, 0.f};
#pragma unroll
    for (int ks = 0; ks < 2; ++ks)
#pragma unroll
      for (int mt2 = 0; mt2 < 4; ++mt2) {
        const int row = mt2 * 16 + lx;
        v8bf kf = *(const v8bf*)((const char*)kbuf[pb] + row * 128 +
                                 (((ks * 4 + g) ^ (lx & 7)) * 16));
        S[mt2] = __builtin_amdgcn_mfma_f32_16x16x32_bf16(kf, qf[ks], S[mt2],
                                                         0, 0, 0);
      }
#pragma unroll
    for (int mt2 = 0; mt2 < 4; ++mt2)
      suml += (__builtin_amdgcn_exp2f(S[mt2][0]) +
               __builtin_amdgcn_exp2f(S[mt2][1])) +
              (__builtin_amdgcn_exp2f(S[mt2][2]) +
               __builtin_amdgcn_exp2f(S[mt2][3]));
  }

  // ---- wave-private epilogue (no barrier); residual fold: + query ----
  suml += __shfl_xor(suml, 16);
  suml += __shfl_xor(suml, 32);
#pragma unroll
  for (int reg = 0; reg < 4; ++reg) {
    const int q = l0 + w * 16 + g * 4 + reg;
    const float den = __shfl(suml, g * 4 + reg);
    const float inv = (float)qmask[b * SL + q] / den;
    const size_t rowoff = ((size_t)(b * SL + q)) * NV + h * DH;
#pragma unroll
    for (int dt = 0; dt < 4; ++dt)
      Xout[rowoff + dt * 16 + lx] =
          O[dt][reg] * inv + queryg[rowoff + dt * 16 + lx];
  }
}

// ---------------------------------------------------------------------------
// LayerNorm over last dim (V=1024); input X already contains the residual
// (folded into attn epilogue). Wave-per-row, zero barriers: 4 rows/block,
// lane owns columns lane*4 + i*256, full reduction via shfl_xor butterfly.
__global__ __launch_bounds__(256)
void ln_kernel(const float* __restrict__ X,
               const float* __restrict__ gamma, const float* __restrict__ beta,
               float* __restrict__ out) {
  const int row = blockIdx.x * 4 + (threadIdx.x >> 6);
  const int lane = threadIdx.x & 63;
  const float* xr = X + (size_t)row * NV;
  float4 y[4];
  float s = 0.f, ss = 0.f;
#pragma unroll
  for (int i = 0; i < 4; ++i) {
    const int col = lane * 4 + i * 256;
    y[i] = *(const float4*)(xr + col);
    s  += (y[i].x + y[i].y) + (y[i].z + y[i].w);
    ss += (y[i].x * y[i].x + y[i].y * y[i].y) +
          (y[i].z * y[i].z + y[i].w * y[i].w);
  }
#pragma unroll
  for (int off = 1; off < 64; off <<= 1) {
    s  += __shfl_xor(s, off);
    ss += __shfl_xor(ss, off);
  }
  const float mu   = s * (1.f / NV);
  const float var  = ss * (1.f / NV) - mu * mu;
  const float rstd = rsqrtf(var + LN_EPS);
#pragma unroll
  for (int i = 0; i < 4; ++i) {
    const int col = lane * 4 + i * 256;
    float4 gv = *(const float4*)(gamma + col);
    float4 bv = *(const float4*)(beta + col);
    float4 o;
    o.x = gv.x * (y[i].x - mu) * rstd + bv.x;
    o.y = gv.y * (y[i].y - mu) * rstd + bv.y;
    o.z = gv.z * (y[i].z - mu) * rstd + bv.z;
    o.w = gv.w * (y[i].w - mu) * rstd + bv.w;
    *(float4*)(out + (size_t)row * NV + col) = o;
  }
}

// ---------------------------------------------------------------------------
extern "C" void kernel_launch(void* const* d_in, const int* in_sizes, int n_in,
                              void* d_out, int out_size, void* d_ws, size_t ws_size,
                              hipStream_t stream) {
  const float* query = (const float*)d_in[0];
  const float* key_t = (const float*)d_in[1];
  const float* value = (const float*)d_in[2];
  const float* Wq    = (const float*)d_in[3];
  const float* Wk    = (const float*)d_in[4];
  const float* Wv    = (const float*)d_in[5];
  const float* gamma = (const float*)d_in[6];
  const float* beta  = (const float*)d_in[7];
  const int*   qmask = (const int*)d_in[8];
  const int*   vmask = (const int*)d_in[9];
  float* out = (float*)d_out;

  const size_t per = (size_t)NB * NH * SL * DH;  // 4,194,304 elements
  bf16_t* Qws = (bf16_t*)d_ws;
  bf16_t* Kws = Qws + per;
  bf16_t* Vws = Kws + per;   // transposed [bh][d][m], vm-masked
  bf16_t* Wtb = Vws + per;   // 3 * 1024*1024 bf16 = 6 MB
  bf16_t* Aq  = Wtb + (size_t)3 * NV * NV;  // bf16 casts of query/key/value
  bf16_t* Ak  = Aq + per;
  bf16_t* Av  = Ak + per;

  prep<<<12288 + 768, 256, 0, stream>>>(query, key_t, value, Wq, Wk, Wv,
                                        Aq, Ak, Av, Wtb);
  proj_mfma<<<dim3(32, 8, 3), 256, 0, stream>>>(Aq, Ak, Av, Wtb,
                                                vmask, Qws, Kws, Vws);
  attn_mfma<<<1024, 256, 0, stream>>>(Qws, Kws, Vws, qmask, query, out);
  ln_kernel<<<NB * SL / 4, 256, 0, stream>>>(out, gamma, beta, out);
}